// Round 8
// baseline (333.611 us; speedup 1.0000x reference)
//
#include <hip/hip_runtime.h>
#include <math.h>
#include <stdint.h>

#define SEQ   4096
#define HID   2048
#define HD    128
#define NROWS 16384          // BATCH*SEQ, BATCH=4

typedef __attribute__((ext_vector_type(8))) short bf16x8;   // 8 bf16 = 4 VGPRs
typedef __attribute__((ext_vector_type(4))) float f32x4;

static constexpr float OSCALE = 0.088388347648318447f;  // 1/sqrt(128), post-softmax

// ---- async global->LDS, 16B per lane; LDS dest = wave-uniform base + lane*16.
using gvptr = const __attribute__((address_space(1))) void*;
using lvptr = __attribute__((address_space(3))) void*;
__device__ __forceinline__ void gld_lds16(const void* g, void* l) {
    __builtin_amdgcn_global_load_lds((gvptr)g, (lvptr)l, 16, 0, 0);
}

// ---- bf16 helpers (manual: storage is ushort)
__device__ __forceinline__ unsigned short f2bf_rne(float f) {
    union { float f; unsigned u; } v; v.f = f;
    unsigned u = v.u + 0x7fffu + ((v.u >> 16) & 1u);
    return (unsigned short)(u >> 16);
}
__device__ __forceinline__ unsigned short f2bf_tr(float f) {
    union { float f; unsigned u; } v; v.f = f;
    return (unsigned short)(v.u >> 16);
}
__device__ __forceinline__ float bf2f(unsigned short h) {
    union { unsigned u; float f; } v; v.u = ((unsigned)h) << 16;
    return v.f;
}

// ---------------------------------------------------------------------------
// prep_w: W[k][n] fp32 -> transposed bf16 hi/lo Wt[n][k] per matrix.
// ---------------------------------------------------------------------------
__global__ __launch_bounds__(256) void prep_w(
    const float* __restrict__ Wq, const float* __restrict__ Wk, const float* __restrict__ Wv,
    unsigned short* __restrict__ wth, unsigned short* __restrict__ wtl)
{
    __shared__ float T[64][68];
    const int tid = threadIdx.x;
    const int k0 = blockIdx.x * 64, n0 = blockIdx.y * 64, mm = blockIdx.z;
    const float* W = (mm == 0) ? Wq : (mm == 1) ? Wk : Wv;
    #pragma unroll
    for (int i = 0; i < 4; ++i) {
        const int fi = i * 256 + tid, kk = fi >> 4, nc = (fi & 15) * 4;
        const float4 w = *(const float4*)(W + (size_t)(k0 + kk) * HD + n0 + nc);
        T[kk][nc] = w.x; T[kk][nc + 1] = w.y; T[kk][nc + 2] = w.z; T[kk][nc + 3] = w.w;
    }
    __syncthreads();
    unsigned short* oh = wth + (size_t)mm * HD * HID;
    unsigned short* ol = wtl + (size_t)mm * HD * HID;
    #pragma unroll
    for (int i = 0; i < 4; ++i) {
        const int fi = i * 256 + tid, nn = fi >> 4, kc = (fi & 15) * 4;
        const float a = T[kc][nn], b = T[kc + 1][nn], c = T[kc + 2][nn], d = T[kc + 3][nn];
        ushort4 hv, lv;
        hv.x = f2bf_rne(a); hv.y = f2bf_rne(b); hv.z = f2bf_rne(c); hv.w = f2bf_rne(d);
        lv.x = f2bf_rne(a - bf2f(hv.x)); lv.y = f2bf_rne(b - bf2f(hv.y));
        lv.z = f2bf_rne(c - bf2f(hv.z)); lv.w = f2bf_rne(d - bf2f(hv.w));
        *(ushort4*)(oh + (size_t)(n0 + nn) * HID + k0 + kc) = hv;
        *(ushort4*)(ol + (size_t)(n0 + nn) * HID + k0 + kc) = lv;
    }
}

// ---------------------------------------------------------------------------
// qkv_split (R14): A-DOUBLE-BUFFER — convert moved out of the barrier window.
// R13 analysis: qkv is 2.4x above max(HBM 42µs, MFMA 25µs) floor; the
// bar->bar window serializes stage-issue + CONVERT(34 VALU + 8 ds_write) +
// drain every iter. Now: bar_a -> stage B(i) -> bar_b -> convert x(i+1) into
// A[p^1] (runs under MFMA's shadow, separate pipes m114) -> prefetch x(i+2)
// -> MFMA on A[p]. Window shrinks to stage+drain (~450cy). All conversions /
// MFMA order bit-identical to R8. Cost: LDS 48->64KB => 2 blocks/CU (R8
// measured 3->2 = -4%); convert-removal must beat that.
// ---------------------------------------------------------------------------
__global__ __launch_bounds__(256, 2) void qkv_split(
    const float* __restrict__ x,
    const float* __restrict__ bq, const float* __restrict__ bk, const float* __restrict__ bv,
    const unsigned short* __restrict__ wth, const unsigned short* __restrict__ wtl,
    unsigned short* __restrict__ qh, unsigned short* __restrict__ ql,
    unsigned short* __restrict__ kh, unsigned short* __restrict__ kl,
    unsigned short* __restrict__ vth)
{
    __shared__ unsigned short Ah[2][64][64], Al[2][64][64];  // x hi/lo, dbuf, swizzled
    __shared__ unsigned short Bh[128][64], Bl[128][64];      // weights, swizzled

    const int tid = threadIdx.x, wave = tid >> 6, lane = tid & 63;
    const int l15 = lane & 15, q4 = lane >> 4;
    const int wr = wave >> 1, wc = wave & 1;              // wave tile: 32 rows x 64 cols
    const int type = blockIdx.x % 3;                      // 0=Q 1=K 2=V
    const int tile = blockIdx.x / 3;
    const int r0 = tile * 64;
    const bool qk = (type < 2);

    const unsigned short* wh = wth + (size_t)type * HD * HID;
    const unsigned short* wl = wtl + (size_t)type * HD * HID;

    // staging geometry: lane -> row offset in 8-row group, XOR'd source chunk
    const int srow   = lane >> 3;                      // 0..7
    const int schunk = ((lane & 7) ^ srow) * 8;        // shorts

    f32x4 acc[2][4];
    #pragma unroll
    for (int mt = 0; mt < 2; ++mt)
        #pragma unroll
        for (int nt = 0; nt < 4; ++nt)
            acc[mt][nt] = (f32x4){0.f, 0.f, 0.f, 0.f};

    const float* xbase = x + (size_t)r0 * HID;

    float4 xv[4];
    // load slab 0
    #pragma unroll
    for (int i = 0; i < 4; ++i) {
        const int fi = i * 256 + tid, row = fi >> 4, kc = (fi & 15) * 4;
        xv[i] = *(const float4*)(xbase + (size_t)row * HID + kc);
    }
    // convert slab 0 -> A[0] (pre-loop; visible to all after first barrier)
    #pragma unroll
    for (int i = 0; i < 4; ++i) {
        const int fi = i * 256 + tid, row = fi >> 4, kc = (fi & 15) * 4;
        const int pk = ((kc >> 3) ^ (row & 7)) * 8 + (kc & 7);
        ushort4 hv;
        hv.x = f2bf_tr(xv[i].x); hv.y = f2bf_tr(xv[i].y);
        hv.z = f2bf_tr(xv[i].z); hv.w = f2bf_tr(xv[i].w);
        *(ushort4*)&Ah[0][row][pk] = hv;
        if (qk) {
            ushort4 lv;
            lv.x = f2bf_tr(xv[i].x - bf2f(hv.x)); lv.y = f2bf_tr(xv[i].y - bf2f(hv.y));
            lv.z = f2bf_tr(xv[i].z - bf2f(hv.z)); lv.w = f2bf_tr(xv[i].w - bf2f(hv.w));
            *(ushort4*)&Al[0][row][pk] = lv;
        }
    }
    // load slab 1 (converted during iter 0, under MFMA's shadow)
    #pragma unroll
    for (int i = 0; i < 4; ++i) {
        const int fi = i * 256 + tid, row = fi >> 4, kc = (fi & 15) * 4;
        xv[i] = *(const float4*)(xbase + (size_t)row * HID + 64 + kc);
    }

    for (int it = 0; it < 32; ++it) {
        const int k0 = it * 64;
        const int p = it & 1;

        __syncthreads();   // bar_a: all waves done reading B(it-1)

        {   // stage weight tiles for this k-slab (L2-hot)
            #pragma unroll
            for (int c = 0; c < 4; ++c) {
                const int row = wave * 32 + c * 8;
                gld_lds16(wh + (size_t)(row + srow) * HID + k0 + schunk, &Bh[row][0]);
            }
            if (qk) {
                #pragma unroll
                for (int c = 0; c < 4; ++c) {
                    const int row = wave * 32 + c * 8;
                    gld_lds16(wl + (size_t)(row + srow) * HID + k0 + schunk, &Bl[row][0]);
                }
            }
        }

        __syncthreads();   // bar_b: B(it) + A[p] (written last iter) visible

        // convert slab it+1 -> A[p^1] (xv holds it; runs under MFMA shadow)
        #pragma unroll
        for (int i = 0; i < 4; ++i) {
            const int fi = i * 256 + tid, row = fi >> 4, kc = (fi & 15) * 4;
            const int pk = ((kc >> 3) ^ (row & 7)) * 8 + (kc & 7);
            ushort4 hv;
            hv.x = f2bf_tr(xv[i].x); hv.y = f2bf_tr(xv[i].y);
            hv.z = f2bf_tr(xv[i].z); hv.w = f2bf_tr(xv[i].w);
            *(ushort4*)&Ah[p ^ 1][row][pk] = hv;
            if (qk) {
                ushort4 lv;
                lv.x = f2bf_tr(xv[i].x - bf2f(hv.x)); lv.y = f2bf_tr(xv[i].y - bf2f(hv.y));
                lv.z = f2bf_tr(xv[i].z - bf2f(hv.z)); lv.w = f2bf_tr(xv[i].w - bf2f(hv.w));
                *(ushort4*)&Al[p ^ 1][row][pk] = lv;
            }
        }
        // prefetch slab it+2 — consumed next iter's convert; MFMA below covers
        {
            const int kn = (k0 + 128) & (HID - 1);
            #pragma unroll
            for (int i = 0; i < 4; ++i) {
                const int fi = i * 256 + tid, row = fi >> 4, kc = (fi & 15) * 4;
                xv[i] = *(const float4*)(xbase + (size_t)row * HID + kn + kc);
            }
        }

        // MFMA on A[p], B(it) — identical sequence/order to R8
        #pragma unroll
        for (int ks = 0; ks < 2; ++ks) {
            const int pc = ((ks * 4 + q4) ^ (l15 & 7)) * 8;   // swizzled chunk (shorts)
            bf16x8 ah[2], al[2];
            #pragma unroll
            for (int mt = 0; mt < 2; ++mt) {
                const int ar = wr * 32 + mt * 16 + l15;
                ah[mt] = *(const bf16x8*)&Ah[p][ar][pc];
                if (qk) al[mt] = *(const bf16x8*)&Al[p][ar][pc];
            }
            #pragma unroll
            for (int nt = 0; nt < 4; ++nt) {
                const int br = wc * 64 + nt * 16 + l15;
                const bf16x8 bh = *(const bf16x8*)&Bh[br][pc];
                #pragma unroll
                for (int mt = 0; mt < 2; ++mt)
                    acc[mt][nt] = __builtin_amdgcn_mfma_f32_16x16x32_bf16(ah[mt], bh, acc[mt][nt], 0, 0, 0);
                if (qk) {
                    const bf16x8 bl = *(const bf16x8*)&Bl[br][pc];
                    #pragma unroll
                    for (int mt = 0; mt < 2; ++mt) {
                        acc[mt][nt] = __builtin_amdgcn_mfma_f32_16x16x32_bf16(ah[mt], bl, acc[mt][nt], 0, 0, 0);
                        acc[mt][nt] = __builtin_amdgcn_mfma_f32_16x16x32_bf16(al[mt], bh, acc[mt][nt], 0, 0, 0);
                    }
                }
            }
        }
    }

    // epilogue. C-frag: col=l15(+tile), rows=q4*4+reg.
    if (qk) {
        const float* bb = (type == 0) ? bq : bk;
        unsigned short* oh = (type == 0) ? qh : kh;
        unsigned short* ol = (type == 0) ? ql : kl;
        #pragma unroll
        for (int nt = 0; nt < 4; ++nt) {
            const int col = wc * 64 + nt * 16 + l15;
            const float bias = bb[col];
            #pragma unroll
            for (int mt = 0; mt < 2; ++mt) {
                const int Rb = r0 + wr * 32 + mt * 16 + q4 * 4;
                #pragma unroll
                for (int r = 0; r < 4; ++r) {
                    const float v = acc[mt][nt][r] + bias;
                    const unsigned short h = f2bf_rne(v);
                    oh[(size_t)(Rb + r) * HD + col] = h;
                    ol[(size_t)(Rb + r) * HD + col] = f2bf_rne(v - bf2f(h));
                }
            }
        }
    } else {
        #pragma unroll
        for (int nt = 0; nt < 4; ++nt) {
            const int col = wc * 64 + nt * 16 + l15;
            const float bias = bv[col];
            #pragma unroll
            for (int mt = 0; mt < 2; ++mt) {
                const int Rb = r0 + wr * 32 + mt * 16 + q4 * 4;
                const int bi = Rb >> 12, s0 = Rb & 4095;   // V transposed: regs = consecutive s
                ushort4 pv;
                pv.x = f2bf_rne(acc[mt][nt][0] + bias);
                pv.y = f2bf_rne(acc[mt][nt][1] + bias);
                pv.z = f2bf_rne(acc[mt][nt][2] + bias);
                pv.w = f2bf_rne(acc[mt][nt][3] + bias);
                *(ushort4*)(vth + ((size_t)(bi * HD + col)) * SEQ + s0) = pv;
            }
        }
    }
}

// ---------------------------------------------------------------------------
// flash_mfma (R13, frozen): swapped QK^T + lane-local softmax + defer-max +
// in-register P transpose (no Ps LDS), one tile/block heavy-first, 3 blk/CU.
// ---------------------------------------------------------------------------
__global__ __launch_bounds__(256, 3) void flash_mfma(
    const unsigned short* __restrict__ qh, const unsigned short* __restrict__ ql,
    const unsigned short* __restrict__ kh, const unsigned short* __restrict__ kl,
    const unsigned short* __restrict__ vth,
    unsigned short* __restrict__ oPb, float* __restrict__ mP, float* __restrict__ lP)
{
    __shared__ unsigned short Kh[64][128], Kl[64][128];   // [kvrow][d], swizzled
    __shared__ unsigned short Vt[128][64];                // [d][kvrow], swizzled

    const int tid = threadIdx.x, wave = tid >> 6, lane = tid & 63;
    const int l15 = lane & 15, q4 = lane >> 4;
    const int b = blockIdx.x & 3, h = (blockIdx.x >> 2) & 3, tord = blockIdx.x >> 4;
    const int tt = 63 - tord;
    const int n = tt + 1;
    const int j0 = (n * h) >> 2, j1 = (n * (h + 1)) >> 2;

    const int krow_l = lane >> 4;                               // 0..3
    const int vrow_l = lane >> 3;                               // 0..7
    const int vsc = ((lane & 7) ^ (vrow_l & 7)) * 8;            // Vt src chunk
    const int kkey7 = l15 & 7;
    const int vkey7 = l15 & 7;

    const int qrow = b * SEQ + tt * 64 + wave * 16 + l15;
    bf16x8 aqh[4], aql[4];
    #pragma unroll
    for (int ks = 0; ks < 4; ++ks) {
        aqh[ks] = *(const bf16x8*)(qh + (size_t)qrow * HD + ks * 32 + q4 * 8);
        aql[ks] = *(const bf16x8*)(ql + (size_t)qrow * HD + ks * 32 + q4 * 8);
    }
    f32x4 oa[8];
    #pragma unroll
    for (int d = 0; d < 8; ++d) oa[d] = (f32x4){0.f, 0.f, 0.f, 0.f};
    float m_r = -INFINITY;   // per-lane softmax state, q = wave*16 + l15
    float l_r = 0.f;

    for (int j = j0; j < j1; ++j) {
        __syncthreads();
        {   // stage K hi/lo + Vt, chunk-swizzled
            const size_t kb = (size_t)b * SEQ + j * 64;
            #pragma unroll
            for (int c = 0; c < 4; ++c) {
                const int rl = c * 4 + krow_l;
                const int sc = (l15 ^ (rl & 7)) * 8;
                const size_t gr = (kb + wave * 16 + rl) * HD + sc;
                gld_lds16(kh + gr, &Kh[wave * 16 + c * 4][0]);
                gld_lds16(kl + gr, &Kl[wave * 16 + c * 4][0]);
            }
            #pragma unroll
            for (int c = 0; c < 4; ++c)
                gld_lds16(vth + ((size_t)(b * HD + wave * 32 + c * 8 + vrow_l)) * SEQ
                              + j * 64 + vsc,
                          &Vt[wave * 32 + c * 8][0]);
        }
        __syncthreads();

        // S^T = K . Q^T : s[nt][r] = S[kv = nt*16+q4*4+r][q = wave*16+l15]
        f32x4 s[4];
        #pragma unroll
        for (int nt = 0; nt < 4; ++nt) s[nt] = (f32x4){0.f, 0.f, 0.f, 0.f};
        __builtin_amdgcn_s_setprio(1);
        #pragma unroll
        for (int ks = 0; ks < 4; ++ks) {
            const int pc = ((ks * 4 + q4) ^ kkey7) * 8;
            #pragma unroll
            for (int nt = 0; nt < 4; ++nt) {
                const bf16x8 bh = *(const bf16x8*)&Kh[nt * 16 + l15][pc];
                const bf16x8 bl = *(const bf16x8*)&Kl[nt * 16 + l15][pc];
                s[nt] = __builtin_amdgcn_mfma_f32_16x16x32_bf16(bh, aqh[ks], s[nt], 0, 0, 0);
                s[nt] = __builtin_amdgcn_mfma_f32_16x16x32_bf16(bh, aql[ks], s[nt], 0, 0, 0);
                s[nt] = __builtin_amdgcn_mfma_f32_16x16x32_bf16(bl, aqh[ks], s[nt], 0, 0, 0);
            }
        }
        __builtin_amdgcn_s_setprio(0);

        if (j == tt) {   // causal mask: kv_local > q_local
            const int qloc = wave * 16 + l15;
            #pragma unroll
            for (int nt = 0; nt < 4; ++nt)
                #pragma unroll
                for (int r = 0; r < 4; ++r) {
                    const int kvl = nt * 16 + q4 * 4 + r;
                    if (kvl > qloc) s[nt][r] = -INFINITY;
                }
        }

        // lane-local softmax over the 16 regs + cross-q4 combine
        float mt = fmaxf(fmaxf(s[0][0], s[0][1]), fmaxf(s[0][2], s[0][3]));
        #pragma unroll
        for (int nt = 1; nt < 4; ++nt)
            mt = fmaxf(mt, fmaxf(fmaxf(s[nt][0], s[nt][1]), fmaxf(s[nt][2], s[nt][3])));
        mt = fmaxf(mt, __shfl_xor(mt, 16));
        mt = fmaxf(mt, __shfl_xor(mt, 32));

        const bool allskip = __all(mt <= m_r + 8.f);   // T13 defer-max
        const float mn = allskip ? m_r : fmaxf(m_r, mt);

        f32x4 pf[4];
        #pragma unroll
        for (int nt = 0; nt < 4; ++nt)
            #pragma unroll
            for (int r = 0; r < 4; ++r)
                pf[nt][r] = __expf(s[nt][r] - mn);

        float ps = ((pf[0][0] + pf[0][1]) + (pf[0][2] + pf[0][3]))
                 + ((pf[1][0] + pf[1][1]) + (pf[1][2] + pf[1][3]))
                 + ((pf[2][0] + pf[2][1]) + (pf[2][2] + pf[2][3]))
                 + ((pf[3][0] + pf[3][1]) + (pf[3][2] + pf[3][3]));
        ps += __shfl_xor(ps, 16);
        ps += __shfl_xor(ps, 32);

        if (allskip) {
            l_r += ps;
        } else {
            const float al = __expf(m_r - mn);
            m_r = mn;
            l_r = l_r * al + ps;
            #pragma unroll
            for (int r = 0; r < 4; ++r) {
                const float alr = __shfl(al, (q4 << 2) | r);
                #pragma unroll
                for (int d = 0; d < 8; ++d) oa[d][r] *= alr;
            }
        }

        // ---- in-register P transpose (no LDS) ----
        unsigned cc[4][2];
        #pragma unroll
        for (int nt = 0; nt < 4; ++nt) {
            cc[nt][0] = (unsigned)f2bf_tr(pf[nt][0]) | ((unsigned)f2bf_tr(pf[nt][1]) << 16);
            cc[nt][1] = (unsigned)f2bf_tr(pf[nt][2]) | ((unsigned)f2bf_tr(pf[nt][3]) << 16);
        }
        unsigned t0[2], t1[2], t2[2], t3[2];
        #pragma unroll
        for (int d = 0; d < 2; ++d) {
            t0[d] = (unsigned)__shfl_xor((int)cc[0][d], 16);
            t1[d] = (unsigned)__shfl_xor((int)cc[1][d], 16);
            t2[d] = (unsigned)__shfl_xor((int)cc[2][d], 16);
            t3[d] = (unsigned)__shfl_xor((int)cc[3][d], 16);
        }
        const bool ev = (q4 & 1) == 0;
        unsigned X0[2], X1[2], X2[2], X3[2];
        #pragma unroll
        for (int d = 0; d < 2; ++d) {
            X0[d] = ev ? cc[0][d] : t1[d];
            X1[d] = ev ? t0[d] : cc[1][d];
            X2[d] = ev ? cc[2][d] : t3[d];
            X3[d] = ev ? t2[d] : cc[3][d];
        }
        const int srcl = ((((q4 & 1) << 1) | (q4 >> 1)) << 4) | l15;
        union { unsigned u[4]; bf16x8 v; } A0, A1;
        A0.u[0] = (unsigned)__shfl((int)X0[0], srcl);
        A0.u[1] = (unsigned)__shfl((int)X0[1], srcl);
        A0.u[2] = (unsigned)__shfl((int)X1[0], srcl);
        A0.u[3] = (unsigned)__shfl((int)X1[1], srcl);
        A1.u[0] = (unsigned)__shfl((int)X2[0], srcl);
        A1.u[1] = (unsigned)__shfl((int)X2[1], srcl);
        A1.u[2] = (unsigned)__shfl((int)X3[0], srcl);
        A1.u[3] = (unsigned)__shfl((int)X3[1], srcl);

        // PV: A = P[q][kv] (register-only), B = Vt
        __builtin_amdgcn_s_setprio(1);
        #pragma unroll
        for (int d = 0; d < 8; ++d) {
            const bf16x8 bv0 = *(const bf16x8*)&Vt[d * 16 + l15][(q4 ^ vkey7) * 8];
            const bf16x8 bv1 = *(const bf16x8*)&Vt[d * 16 + l15][((4 + q4) ^ vkey7) * 8];
            oa[d] = __builtin_amdgcn_mfma_f32_16x16x32_bf16(A0.v, bv0, oa[d], 0, 0, 0);
            oa[d] = __builtin_amdgcn_mfma_f32_16x16x32_bf16(A1.v, bv1, oa[d], 0, 0, 0);
        }
        __builtin_amdgcn_s_setprio(0);
    }

    // epilogue: O rows; m/l per-lane (q = wave*16+l15), q4==0 lanes write
    const int R0 = b * SEQ + tt * 64 + wave * 16 + q4 * 4;
    unsigned short* op = oPb + (size_t)h * NROWS * HD;
    #pragma unroll
    for (int d = 0; d < 8; ++d)
        #pragma unroll
        for (int r = 0; r < 4; ++r)
            op[(size_t)(R0 + r) * HD + d * 16 + l15] = f2bf_rne(oa[d][r]);
    if (q4 == 0) {
        const int qr = b * SEQ + tt * 64 + wave * 16 + l15;
        mP[h * NROWS + qr] = m_r;
        lP[h * NROWS + qr] = l_r;
    }
}

// ---------------------------------------------------------------------------
// merge the four kv-quarter partials; apply 1/l and OSCALE.
// ---------------------------------------------------------------------------
__global__ __launch_bounds__(256) void flash_merge(
    const unsigned short* __restrict__ oPb, const float* __restrict__ mP,
    const float* __restrict__ lP, float* __restrict__ out)
{
    const int idx = blockIdx.x * 256 + threadIdx.x;   // per float4
    const int r = idx >> 5, c = (idx & 31) * 4;
    float m[4], l[4];
    #pragma unroll
    for (int i = 0; i < 4; ++i) { m[i] = mP[i * NROWS + r]; l[i] = lP[i * NROWS + r]; }
    float M = fmaxf(fmaxf(m[0], m[1]), fmaxf(m[2], m[3]));
    float a[4], lsum = 0.f;
    #pragma unroll
    for (int i = 0; i < 4; ++i) { a[i] = __expf(m[i] - M); lsum += l[i] * a[i]; }
    const float inv = OSCALE / lsum;
    float ox = 0.f, oy = 0.f, oz = 0.f, ow = 0.f;
    #pragma unroll
    for (int i = 0; i < 4; ++i) {
        const ushort4 ov = *(const ushort4*)(oPb + (size_t)i * NROWS * HD + (size_t)r * HD + c);
        ox += a[i] * bf2f(ov.x); oy += a[i] * bf2f(ov.y);
        oz += a[i] * bf2f(ov.z); ow += a[i] * bf2f(ov.w);
    }
    float4 o; o.x = ox * inv; o.y = oy * inv; o.z = oz * inv; o.w = ow * inv;
    *(float4*)(out + (size_t)r * HD + c) = o;
}

// ---------------------------------------------------------------------------
extern "C" void kernel_launch(void* const* d_in, const int* in_sizes, int n_in,
                              void* d_out, int out_size, void* d_ws, size_t ws_size,
                              hipStream_t stream)
{
    (void)in_sizes; (void)n_in; (void)out_size; (void)ws_size;
    const float* x  = (const float*)d_in[0];
    const float* Wq = (const float*)d_in[1];
    const float* bq = (const float*)d_in[2];
    const float* Wk = (const float*)d_in[3];
    const float* bk = (const float*)d_in[4];
    const float* Wv = (const float*)d_in[5];
    const float* bv = (const float*)d_in[6];
    float* out = (float*)d_out;

    // workspace layout (bytes): ~41.4 MB total
    char* w = (char*)d_ws;
    unsigned short* qh  = (unsigned short*)(w);
    unsigned short* ql  = (unsigned short*)(w + 4194304);
    unsigned short* kh  = (unsigned short*)(w + 8388608);
    unsigned short* kl  = (unsigned short*)(w + 12582912);
    unsigned short* vth = (unsigned short*)(w + 16777216);
    unsigned short* wth = (unsigned short*)(w + 20971520);
    unsigned short* wtl = (unsigned short*)(w + 22544384);
    unsigned short* oPb = (unsigned short*)(w + 24117248);   // 4 x NROWS x HD bf16
    float* mP = (float*)(w + 40894464);                      // 4 x NROWS
    float* lP = (float*)(w + 41156608);                      // 4 x NROWS

    prep_w<<<dim3(32, 2, 3), 256, 0, stream>>>(Wq, Wk, Wv, wth, wtl);
    qkv_split<<<768, 256, 0, stream>>>(x, bq, bk, bv, wth, wtl, qh, ql, kh, kl, vth);
    flash_mfma<<<1024, 256, 0, stream>>>(qh, ql, kh, kl, vth, oPb, mP, lP);
    flash_merge<<<2048, 256, 0, stream>>>(oPb, mP, lP, out);
}

// Round 9
// 303.738 us; speedup vs baseline: 1.0983x; 1.0983x over previous
//
#include <hip/hip_runtime.h>
#include <math.h>
#include <stdint.h>

#define SEQ   4096
#define HID   2048
#define HD    128
#define NROWS 16384          // BATCH*SEQ, BATCH=4

typedef __attribute__((ext_vector_type(8))) short bf16x8;   // 8 bf16 = 4 VGPRs
typedef __attribute__((ext_vector_type(4))) float f32x4;

static constexpr float OSCALE = 0.088388347648318447f;  // 1/sqrt(128), post-softmax

// ---- async global->LDS, 16B per lane; LDS dest = wave-uniform base + lane*16.
using gvptr = const __attribute__((address_space(1))) void*;
using lvptr = __attribute__((address_space(3))) void*;
__device__ __forceinline__ void gld_lds16(const void* g, void* l) {
    __builtin_amdgcn_global_load_lds((gvptr)g, (lvptr)l, 16, 0, 0);
}

// ---- bf16 helpers (manual: storage is ushort)
__device__ __forceinline__ unsigned short f2bf_rne(float f) {
    union { float f; unsigned u; } v; v.f = f;
    unsigned u = v.u + 0x7fffu + ((v.u >> 16) & 1u);
    return (unsigned short)(u >> 16);
}
__device__ __forceinline__ unsigned short f2bf_tr(float f) {
    union { float f; unsigned u; } v; v.f = f;
    return (unsigned short)(v.u >> 16);
}
__device__ __forceinline__ float bf2f(unsigned short h) {
    union { unsigned u; float f; } v; v.u = ((unsigned)h) << 16;
    return v.f;
}

// ---------------------------------------------------------------------------
// prep_w: W[k][n] fp32 -> transposed bf16 hi/lo Wt[n][k] per matrix.
// ---------------------------------------------------------------------------
__global__ __launch_bounds__(256) void prep_w(
    const float* __restrict__ Wq, const float* __restrict__ Wk, const float* __restrict__ Wv,
    unsigned short* __restrict__ wth, unsigned short* __restrict__ wtl)
{
    __shared__ float T[64][68];
    const int tid = threadIdx.x;
    const int k0 = blockIdx.x * 64, n0 = blockIdx.y * 64, mm = blockIdx.z;
    const float* W = (mm == 0) ? Wq : (mm == 1) ? Wk : Wv;
    #pragma unroll
    for (int i = 0; i < 4; ++i) {
        const int fi = i * 256 + tid, kk = fi >> 4, nc = (fi & 15) * 4;
        const float4 w = *(const float4*)(W + (size_t)(k0 + kk) * HD + n0 + nc);
        T[kk][nc] = w.x; T[kk][nc + 1] = w.y; T[kk][nc + 2] = w.z; T[kk][nc + 3] = w.w;
    }
    __syncthreads();
    unsigned short* oh = wth + (size_t)mm * HD * HID;
    unsigned short* ol = wtl + (size_t)mm * HD * HID;
    #pragma unroll
    for (int i = 0; i < 4; ++i) {
        const int fi = i * 256 + tid, nn = fi >> 4, kc = (fi & 15) * 4;
        const float a = T[kc][nn], b = T[kc + 1][nn], c = T[kc + 2][nn], d = T[kc + 3][nn];
        ushort4 hv, lv;
        hv.x = f2bf_rne(a); hv.y = f2bf_rne(b); hv.z = f2bf_rne(c); hv.w = f2bf_rne(d);
        lv.x = f2bf_rne(a - bf2f(hv.x)); lv.y = f2bf_rne(b - bf2f(hv.y));
        lv.z = f2bf_rne(c - bf2f(hv.z)); lv.w = f2bf_rne(d - bf2f(hv.w));
        *(ushort4*)(oh + (size_t)(n0 + nn) * HID + k0 + kc) = hv;
        *(ushort4*)(ol + (size_t)(n0 + nn) * HID + k0 + kc) = lv;
    }
}

// ---------------------------------------------------------------------------
// qkv_split (R8 verbatim — 100.8/101.2/101.0/100.2 µs across runs; MfmaUtil
// 24.5, conflicts 0, 3 blocks/CU). R14's A-dbuf regressed (stage-drain left
// uncovered + occupancy loss); this is the proven plateau structure.
// ---------------------------------------------------------------------------
__global__ __launch_bounds__(256, 3) void qkv_split(
    const float* __restrict__ x,
    const float* __restrict__ bq, const float* __restrict__ bk, const float* __restrict__ bv,
    const unsigned short* __restrict__ wth, const unsigned short* __restrict__ wtl,
    unsigned short* __restrict__ qh, unsigned short* __restrict__ ql,
    unsigned short* __restrict__ kh, unsigned short* __restrict__ kl,
    unsigned short* __restrict__ vth)
{
    __shared__ unsigned short Ah[64][64], Al[64][64];     // x hi/lo, chunk-swizzled
    __shared__ unsigned short Bh[128][64], Bl[128][64];   // weight hi/lo, chunk-swizzled

    const int tid = threadIdx.x, wave = tid >> 6, lane = tid & 63;
    const int l15 = lane & 15, q4 = lane >> 4;
    const int wr = wave >> 1, wc = wave & 1;              // wave tile: 32 rows x 64 cols
    const int type = blockIdx.x % 3;                      // 0=Q 1=K 2=V
    const int tile = blockIdx.x / 3;
    const int r0 = tile * 64;
    const bool qk = (type < 2);

    const unsigned short* wh = wth + (size_t)type * HD * HID;
    const unsigned short* wl = wtl + (size_t)type * HD * HID;

    // staging geometry: lane -> row offset in 8-row group, XOR'd source chunk
    const int srow   = lane >> 3;                      // 0..7
    const int schunk = ((lane & 7) ^ srow) * 8;        // shorts

    f32x4 acc[2][4];
    #pragma unroll
    for (int mt = 0; mt < 2; ++mt)
        #pragma unroll
        for (int nt = 0; nt < 4; ++nt)
            acc[mt][nt] = (f32x4){0.f, 0.f, 0.f, 0.f};

    const float* xbase = x + (size_t)r0 * HID;

    // preload first x slab (64 rows x 64 k): 4 float4 per thread
    float4 xv[4];
    #pragma unroll
    for (int i = 0; i < 4; ++i) {
        const int fi = i * 256 + tid, row = fi >> 4, kc = (fi & 15) * 4;
        xv[i] = *(const float4*)(xbase + (size_t)row * HID + kc);
    }

    for (int k0 = 0; k0 < HID; k0 += 64) {
        __syncthreads();   // prior iter's frag reads done

        {   // stage weight tiles for this k-slab (L2-hot, covered by convert)
            #pragma unroll
            for (int c = 0; c < 4; ++c) {
                const int row = wave * 32 + c * 8;
                gld_lds16(wh + (size_t)(row + srow) * HID + k0 + schunk, &Bh[row][0]);
            }
            if (qk) {
                #pragma unroll
                for (int c = 0; c < 4; ++c) {
                    const int row = wave * 32 + c * 8;
                    gld_lds16(wl + (size_t)(row + srow) * HID + k0 + schunk, &Bl[row][0]);
                }
            }
        }
        #pragma unroll
        for (int i = 0; i < 4; ++i) {   // convert current x slab -> LDS (swizzled)
            const int fi = i * 256 + tid, row = fi >> 4, kc = (fi & 15) * 4;
            const int pk = ((kc >> 3) ^ (row & 7)) * 8 + (kc & 7);   // phys shorts
            ushort4 hv;
            hv.x = f2bf_tr(xv[i].x); hv.y = f2bf_tr(xv[i].y);
            hv.z = f2bf_tr(xv[i].z); hv.w = f2bf_tr(xv[i].w);
            *(ushort4*)&Ah[row][pk] = hv;
            if (qk) {
                ushort4 lv;
                lv.x = f2bf_tr(xv[i].x - bf2f(hv.x)); lv.y = f2bf_tr(xv[i].y - bf2f(hv.y));
                lv.z = f2bf_tr(xv[i].z - bf2f(hv.z)); lv.w = f2bf_tr(xv[i].w - bf2f(hv.w));
                *(ushort4*)&Al[row][pk] = lv;
            }
        }
        __syncthreads();

        // prefetch NEXT x slab now — consumed next iteration (HBM latency
        // hidden behind the MFMA section below)
        const int kn = (k0 + 64 < HID) ? (k0 + 64) : 0;
        #pragma unroll
        for (int i = 0; i < 4; ++i) {
            const int fi = i * 256 + tid, row = fi >> 4, kc = (fi & 15) * 4;
            xv[i] = *(const float4*)(xbase + (size_t)row * HID + kn + kc);
        }

        #pragma unroll
        for (int ks = 0; ks < 2; ++ks) {
            const int pc = ((ks * 4 + q4) ^ (l15 & 7)) * 8;   // swizzled chunk (shorts)
            bf16x8 ah[2], al[2];
            #pragma unroll
            for (int mt = 0; mt < 2; ++mt) {
                const int ar = wr * 32 + mt * 16 + l15;
                ah[mt] = *(const bf16x8*)&Ah[ar][pc];
                if (qk) al[mt] = *(const bf16x8*)&Al[ar][pc];
            }
            #pragma unroll
            for (int nt = 0; nt < 4; ++nt) {
                const int br = wc * 64 + nt * 16 + l15;
                const bf16x8 bh = *(const bf16x8*)&Bh[br][pc];
                #pragma unroll
                for (int mt = 0; mt < 2; ++mt)
                    acc[mt][nt] = __builtin_amdgcn_mfma_f32_16x16x32_bf16(ah[mt], bh, acc[mt][nt], 0, 0, 0);
                if (qk) {
                    const bf16x8 bl = *(const bf16x8*)&Bl[br][pc];
                    #pragma unroll
                    for (int mt = 0; mt < 2; ++mt) {
                        acc[mt][nt] = __builtin_amdgcn_mfma_f32_16x16x32_bf16(ah[mt], bl, acc[mt][nt], 0, 0, 0);
                        acc[mt][nt] = __builtin_amdgcn_mfma_f32_16x16x32_bf16(al[mt], bh, acc[mt][nt], 0, 0, 0);
                    }
                }
            }
        }
    }

    // epilogue. C-frag: col=l15(+tile), rows=q4*4+reg.
    if (qk) {
        const float* bb = (type == 0) ? bq : bk;
        unsigned short* oh = (type == 0) ? qh : kh;
        unsigned short* ol = (type == 0) ? ql : kl;
        #pragma unroll
        for (int nt = 0; nt < 4; ++nt) {
            const int col = wc * 64 + nt * 16 + l15;
            const float bias = bb[col];
            #pragma unroll
            for (int mt = 0; mt < 2; ++mt) {
                const int Rb = r0 + wr * 32 + mt * 16 + q4 * 4;
                #pragma unroll
                for (int r = 0; r < 4; ++r) {
                    const float v = acc[mt][nt][r] + bias;
                    const unsigned short h = f2bf_rne(v);
                    oh[(size_t)(Rb + r) * HD + col] = h;
                    ol[(size_t)(Rb + r) * HD + col] = f2bf_rne(v - bf2f(h));
                }
            }
        }
    } else {
        #pragma unroll
        for (int nt = 0; nt < 4; ++nt) {
            const int col = wc * 64 + nt * 16 + l15;
            const float bias = bv[col];
            #pragma unroll
            for (int mt = 0; mt < 2; ++mt) {
                const int Rb = r0 + wr * 32 + mt * 16 + q4 * 4;
                const int bi = Rb >> 12, s0 = Rb & 4095;   // V transposed: regs = consecutive s
                ushort4 pv;
                pv.x = f2bf_rne(acc[mt][nt][0] + bias);
                pv.y = f2bf_rne(acc[mt][nt][1] + bias);
                pv.z = f2bf_rne(acc[mt][nt][2] + bias);
                pv.w = f2bf_rne(acc[mt][nt][3] + bias);
                *(ushort4*)(vth + ((size_t)(bi * HD + col)) * SEQ + s0) = pv;
            }
        }
    }
}

// ---------------------------------------------------------------------------
// flash_mfma (R15): R13 math (swapped QK^T, lane-local softmax, defer-max,
// in-register P transpose) + counted-vmcnt K-DOUBLE-BUFFER staging:
//   per iter: issue V(j)[4] -> issue K(j+1)->buf^1[8] -> vmcnt(12) [K(j),
//   issued one full iter ago: free] -> bar -> QK+softmax -> vmcnt(8) [V(j),
//   issued ~1500cy ago, older than K(j+1): in-order retirement correct]
//   -> bar -> P-transpose + PV -> bar [protects Vt & K-buf reuse].
// No vmcnt(0) drain anywhere in the loop (the old stage->syncthreads pattern
// exposed ~400-600cy raw L2 latency per iter). LDS 80KB -> 2 blocks/CU
// (3->2 measured null in R13). Same per-iter work/reads/swizzles/math ->
// bit-identical numerics.
// ---------------------------------------------------------------------------
__global__ __launch_bounds__(256, 2) void flash_mfma(
    const unsigned short* __restrict__ qh, const unsigned short* __restrict__ ql,
    const unsigned short* __restrict__ kh, const unsigned short* __restrict__ kl,
    const unsigned short* __restrict__ vth,
    unsigned short* __restrict__ oPb, float* __restrict__ mP, float* __restrict__ lP)
{
    __shared__ unsigned short Kh2[2][64][128], Kl2[2][64][128];  // dbuf, swizzled
    __shared__ unsigned short Vt[128][64];                       // single, swizzled

    const int tid = threadIdx.x, wave = tid >> 6, lane = tid & 63;
    const int l15 = lane & 15, q4 = lane >> 4;
    const int b = blockIdx.x & 3, h = (blockIdx.x >> 2) & 3, tord = blockIdx.x >> 4;
    const int tt = 63 - tord;
    const int n = tt + 1;
    const int j0 = (n * h) >> 2, j1 = (n * (h + 1)) >> 2;

    const int krow_l = lane >> 4;                               // 0..3
    const int vrow_l = lane >> 3;                               // 0..7
    const int vsc = ((lane & 7) ^ (vrow_l & 7)) * 8;            // Vt src chunk
    const int kkey7 = l15 & 7;
    const int vkey7 = l15 & 7;

    const int qrow = b * SEQ + tt * 64 + wave * 16 + l15;
    bf16x8 aqh[4], aql[4];
    #pragma unroll
    for (int ks = 0; ks < 4; ++ks) {
        aqh[ks] = *(const bf16x8*)(qh + (size_t)qrow * HD + ks * 32 + q4 * 8);
        aql[ks] = *(const bf16x8*)(ql + (size_t)qrow * HD + ks * 32 + q4 * 8);
    }
    f32x4 oa[8];
    #pragma unroll
    for (int d = 0; d < 8; ++d) oa[d] = (f32x4){0.f, 0.f, 0.f, 0.f};
    float m_r = -INFINITY;   // per-lane softmax state, q = wave*16 + l15
    float l_r = 0.f;

    // prologue: stage K(j0) -> buf 0
    if (j0 < j1) {
        const size_t kb0 = (size_t)b * SEQ + j0 * 64;
        #pragma unroll
        for (int c = 0; c < 4; ++c) {
            const int rl = c * 4 + krow_l;
            const int sc = (l15 ^ (rl & 7)) * 8;
            const size_t gr = (kb0 + wave * 16 + rl) * HD + sc;
            gld_lds16(kh + gr, &Kh2[0][wave * 16 + c * 4][0]);
            gld_lds16(kl + gr, &Kl2[0][wave * 16 + c * 4][0]);
        }
    }

    int cur = 0;
    for (int j = j0; j < j1; ++j) {
        // issue V(j) [4 gld_lds] — Vt reuse protected by last iter's end barrier
        #pragma unroll
        for (int c = 0; c < 4; ++c)
            gld_lds16(vth + ((size_t)(b * HD + wave * 32 + c * 8 + vrow_l)) * SEQ
                          + j * 64 + vsc,
                      &Vt[wave * 32 + c * 8][0]);
        // issue K(j+1) -> buf cur^1 [8 gld_lds] (clamped on last iter)
        {
            const int jn = (j + 1 < j1) ? (j + 1) : j;
            const size_t kbn = (size_t)b * SEQ + jn * 64;
            #pragma unroll
            for (int c = 0; c < 4; ++c) {
                const int rl = c * 4 + krow_l;
                const int sc = (l15 ^ (rl & 7)) * 8;
                const size_t gr = (kbn + wave * 16 + rl) * HD + sc;
                gld_lds16(kh + gr, &Kh2[cur ^ 1][wave * 16 + c * 4][0]);
                gld_lds16(kl + gr, &Kl2[cur ^ 1][wave * 16 + c * 4][0]);
            }
        }
        // await K(j): newer outstanding = V(j)[4] + K(j+1)[8] = 12
        asm volatile("s_waitcnt vmcnt(12)" ::: "memory");
        __builtin_amdgcn_sched_barrier(0);
        __builtin_amdgcn_s_barrier();          // K(j) visible block-wide

        // S^T = K . Q^T : s[nt][r] = S[kv = nt*16+q4*4+r][q = wave*16+l15]
        f32x4 s[4];
        #pragma unroll
        for (int nt = 0; nt < 4; ++nt) s[nt] = (f32x4){0.f, 0.f, 0.f, 0.f};
        __builtin_amdgcn_s_setprio(1);
        #pragma unroll
        for (int ks = 0; ks < 4; ++ks) {
            const int pc = ((ks * 4 + q4) ^ kkey7) * 8;
            #pragma unroll
            for (int nt = 0; nt < 4; ++nt) {
                const bf16x8 bh = *(const bf16x8*)&Kh2[cur][nt * 16 + l15][pc];
                const bf16x8 bl = *(const bf16x8*)&Kl2[cur][nt * 16 + l15][pc];
                s[nt] = __builtin_amdgcn_mfma_f32_16x16x32_bf16(bh, aqh[ks], s[nt], 0, 0, 0);
                s[nt] = __builtin_amdgcn_mfma_f32_16x16x32_bf16(bh, aql[ks], s[nt], 0, 0, 0);
                s[nt] = __builtin_amdgcn_mfma_f32_16x16x32_bf16(bl, aqh[ks], s[nt], 0, 0, 0);
            }
        }
        __builtin_amdgcn_s_setprio(0);

        if (j == tt) {   // causal mask: kv_local > q_local
            const int qloc = wave * 16 + l15;
            #pragma unroll
            for (int nt = 0; nt < 4; ++nt)
                #pragma unroll
                for (int r = 0; r < 4; ++r) {
                    const int kvl = nt * 16 + q4 * 4 + r;
                    if (kvl > qloc) s[nt][r] = -INFINITY;
                }
        }

        // lane-local softmax over the 16 regs + cross-q4 combine
        float mt = fmaxf(fmaxf(s[0][0], s[0][1]), fmaxf(s[0][2], s[0][3]));
        #pragma unroll
        for (int nt = 1; nt < 4; ++nt)
            mt = fmaxf(mt, fmaxf(fmaxf(s[nt][0], s[nt][1]), fmaxf(s[nt][2], s[nt][3])));
        mt = fmaxf(mt, __shfl_xor(mt, 16));
        mt = fmaxf(mt, __shfl_xor(mt, 32));

        const bool allskip = __all(mt <= m_r + 8.f);   // T13 defer-max
        const float mn = allskip ? m_r : fmaxf(m_r, mt);

        f32x4 pf[4];
        #pragma unroll
        for (int nt = 0; nt < 4; ++nt)
            #pragma unroll
            for (int r = 0; r < 4; ++r)
                pf[nt][r] = __expf(s[nt][r] - mn);

        float ps = ((pf[0][0] + pf[0][1]) + (pf[0][2] + pf[0][3]))
                 + ((pf[1][0] + pf[1][1]) + (pf[1][2] + pf[1][3]))
                 + ((pf[2][0] + pf[2][1]) + (pf[2][2] + pf[2][3]))
                 + ((pf[3][0] + pf[3][1]) + (pf[3][2] + pf[3][3]));
        ps += __shfl_xor(ps, 16);
        ps += __shfl_xor(ps, 32);

        if (allskip) {
            l_r += ps;
        } else {
            const float al = __expf(m_r - mn);
            m_r = mn;
            l_r = l_r * al + ps;
            #pragma unroll
            for (int r = 0; r < 4; ++r) {
                const float alr = __shfl(al, (q4 << 2) | r);
                #pragma unroll
                for (int d = 0; d < 8; ++d) oa[d][r] *= alr;
            }
        }

        // await V(j): outstanding = V(j)[4, older] + K(j+1)[8, newer] = 12 -> 8
        asm volatile("s_waitcnt vmcnt(8)" ::: "memory");
        __builtin_amdgcn_sched_barrier(0);
        __builtin_amdgcn_s_barrier();          // V(j) visible block-wide

        // ---- in-register P transpose (no LDS) ----
        unsigned cc[4][2];
        #pragma unroll
        for (int nt = 0; nt < 4; ++nt) {
            cc[nt][0] = (unsigned)f2bf_tr(pf[nt][0]) | ((unsigned)f2bf_tr(pf[nt][1]) << 16);
            cc[nt][1] = (unsigned)f2bf_tr(pf[nt][2]) | ((unsigned)f2bf_tr(pf[nt][3]) << 16);
        }
        unsigned t0[2], t1[2], t2[2], t3[2];
        #pragma unroll
        for (int d = 0; d < 2; ++d) {
            t0[d] = (unsigned)__shfl_xor((int)cc[0][d], 16);
            t1[d] = (unsigned)__shfl_xor((int)cc[1][d], 16);
            t2[d] = (unsigned)__shfl_xor((int)cc[2][d], 16);
            t3[d] = (unsigned)__shfl_xor((int)cc[3][d], 16);
        }
        const bool ev = (q4 & 1) == 0;
        unsigned X0[2], X1[2], X2[2], X3[2];
        #pragma unroll
        for (int d = 0; d < 2; ++d) {
            X0[d] = ev ? cc[0][d] : t1[d];
            X1[d] = ev ? t0[d] : cc[1][d];
            X2[d] = ev ? cc[2][d] : t3[d];
            X3[d] = ev ? t2[d] : cc[3][d];
        }
        const int srcl = ((((q4 & 1) << 1) | (q4 >> 1)) << 4) | l15;
        union { unsigned u[4]; bf16x8 v; } A0, A1;
        A0.u[0] = (unsigned)__shfl((int)X0[0], srcl);
        A0.u[1] = (unsigned)__shfl((int)X0[1], srcl);
        A0.u[2] = (unsigned)__shfl((int)X1[0], srcl);
        A0.u[3] = (unsigned)__shfl((int)X1[1], srcl);
        A1.u[0] = (unsigned)__shfl((int)X2[0], srcl);
        A1.u[1] = (unsigned)__shfl((int)X2[1], srcl);
        A1.u[2] = (unsigned)__shfl((int)X3[0], srcl);
        A1.u[3] = (unsigned)__shfl((int)X3[1], srcl);

        // PV: A = P[q][kv] (register-only), B = Vt
        __builtin_amdgcn_s_setprio(1);
        #pragma unroll
        for (int d = 0; d < 8; ++d) {
            const bf16x8 bv0 = *(const bf16x8*)&Vt[d * 16 + l15][(q4 ^ vkey7) * 8];
            const bf16x8 bv1 = *(const bf16x8*)&Vt[d * 16 + l15][((4 + q4) ^ vkey7) * 8];
            oa[d] = __builtin_amdgcn_mfma_f32_16x16x32_bf16(A0.v, bv0, oa[d], 0, 0, 0);
            oa[d] = __builtin_amdgcn_mfma_f32_16x16x32_bf16(A1.v, bv1, oa[d], 0, 0, 0);
        }
        __builtin_amdgcn_s_setprio(0);

        __builtin_amdgcn_s_barrier();   // all PV reads of Vt/K-buf done (MFMA
                                        // data-deps forced lgkm completion)
        cur ^= 1;
    }

    // epilogue: O rows; m/l per-lane (q = wave*16+l15), q4==0 lanes write
    const int R0 = b * SEQ + tt * 64 + wave * 16 + q4 * 4;
    unsigned short* op = oPb + (size_t)h * NROWS * HD;
    #pragma unroll
    for (int d = 0; d < 8; ++d)
        #pragma unroll
        for (int r = 0; r < 4; ++r)
            op[(size_t)(R0 + r) * HD + d * 16 + l15] = f2bf_rne(oa[d][r]);
    if (q4 == 0) {
        const int qr = b * SEQ + tt * 64 + wave * 16 + l15;
        mP[h * NROWS + qr] = m_r;
        lP[h * NROWS + qr] = l_r;
    }
}

// ---------------------------------------------------------------------------
// merge the four kv-quarter partials; apply 1/l and OSCALE.
// ---------------------------------------------------------------------------
__global__ __launch_bounds__(256) void flash_merge(
    const unsigned short* __restrict__ oPb, const float* __restrict__ mP,
    const float* __restrict__ lP, float* __restrict__ out)
{
    const int idx = blockIdx.x * 256 + threadIdx.x;   // per float4
    const int r = idx >> 5, c = (idx & 31) * 4;
    float m[4], l[4];
    #pragma unroll
    for (int i = 0; i < 4; ++i) { m[i] = mP[i * NROWS + r]; l[i] = lP[i * NROWS + r]; }
    float M = fmaxf(fmaxf(m[0], m[1]), fmaxf(m[2], m[3]));
    float a[4], lsum = 0.f;
    #pragma unroll
    for (int i = 0; i < 4; ++i) { a[i] = __expf(m[i] - M); lsum += l[i] * a[i]; }
    const float inv = OSCALE / lsum;
    float ox = 0.f, oy = 0.f, oz = 0.f, ow = 0.f;
    #pragma unroll
    for (int i = 0; i < 4; ++i) {
        const ushort4 ov = *(const ushort4*)(oPb + (size_t)i * NROWS * HD + (size_t)r * HD + c);
        ox += a[i] * bf2f(ov.x); oy += a[i] * bf2f(ov.y);
        oz += a[i] * bf2f(ov.z); ow += a[i] * bf2f(ov.w);
    }
    float4 o; o.x = ox * inv; o.y = oy * inv; o.z = oz * inv; o.w = ow * inv;
    *(float4*)(out + (size_t)r * HD + c) = o;
}

// ---------------------------------------------------------------------------
extern "C" void kernel_launch(void* const* d_in, const int* in_sizes, int n_in,
                              void* d_out, int out_size, void* d_ws, size_t ws_size,
                              hipStream_t stream)
{
    (void)in_sizes; (void)n_in; (void)out_size; (void)ws_size;
    const float* x  = (const float*)d_in[0];
    const float* Wq = (const float*)d_in[1];
    const float* bq = (const float*)d_in[2];
    const float* Wk = (const float*)d_in[3];
    const float* bk = (const float*)d_in[4];
    const float* Wv = (const float*)d_in[5];
    const float* bv = (const float*)d_in[6];
    float* out = (float*)d_out;

    // workspace layout (bytes): ~41.4 MB total
    char* w = (char*)d_ws;
    unsigned short* qh  = (unsigned short*)(w);
    unsigned short* ql  = (unsigned short*)(w + 4194304);
    unsigned short* kh  = (unsigned short*)(w + 8388608);
    unsigned short* kl  = (unsigned short*)(w + 12582912);
    unsigned short* vth = (unsigned short*)(w + 16777216);
    unsigned short* wth = (unsigned short*)(w + 20971520);
    unsigned short* wtl = (unsigned short*)(w + 22544384);
    unsigned short* oPb = (unsigned short*)(w + 24117248);   // 4 x NROWS x HD bf16
    float* mP = (float*)(w + 40894464);                      // 4 x NROWS
    float* lP = (float*)(w + 41156608);                      // 4 x NROWS

    prep_w<<<dim3(32, 2, 3), 256, 0, stream>>>(Wq, Wk, Wv, wth, wtl);
    qkv_split<<<768, 256, 0, stream>>>(x, bq, bk, bv, wth, wtl, qh, ql, kh, kl, vth);
    flash_mfma<<<1024, 256, 0, stream>>>(qh, ql, kh, kl, vth, oPb, mP, lP);
    flash_merge<<<2048, 256, 0, stream>>>(oPb, mP, lP, out);
}